// Round 6
// baseline (248.468 us; speedup 1.0000x reference)
//
#include <hip/hip_runtime.h>

#define B_    16
#define D_    256
#define H_    32
#define W_    32
#define SP    1024        // H_*W_
#define N_TOT 16384       // B_*SP
#define K_    8192
#define ZB    (D_*SP)     // floats per batch in z

#define BIAS_  0.03125f
#define DELTA_ 2.5e-4f

typedef __attribute__((ext_vector_type(8))) short bf16x8;
typedef __attribute__((ext_vector_type(4))) short bf16x4;
typedef __attribute__((ext_vector_type(4))) float f32x4;

#define GLOAD_LDS16(g, l) \
    __builtin_amdgcn_global_load_lds((const __attribute__((address_space(1))) void*)(g), \
                                     (__attribute__((address_space(3))) void*)(l), 16, 0, 0)

__device__ __forceinline__ unsigned short f2bf(float f) {
    unsigned u = __float_as_uint(f);
    u += 0x7FFFu + ((u >> 16) & 1u);          // RNE
    return (unsigned short)(u >> 16);
}

// merge two sorted pairs (a1<=a2), (b1<=b2) -> top-2 in (a1,a2). u32 lex keys.
__device__ __forceinline__ void merge2(unsigned &a1, unsigned &a2,
                                       unsigned b1, unsigned b2) {
    unsigned m1  = min(a1, b1);
    unsigned hi  = max(a1, b1);
    unsigned sel = (a1 < b1) ? a2 : b2;
    a2 = min(hi, sel);
    a1 = m1;
}

// =====================================================================
// ===================  BIG tier (needs 17.04 MB ws)  ==================
// =====================================================================
// Plain row-major bf16 layouts: ET[k][256], ZT[n][256]. Bank swizzle is
// applied in the staging *global* addresses (chunk lc = phys ^ ((row>>1)&3)),
// LDS dest stays linear as global_load_lds requires.

// fused: emb -> enorm/enormB + plain bf16 ET (enorm tree IDENTICAL to r1-5)
__global__ __launch_bounds__(256)
void cvt_e_enorm_p(const float* __restrict__ emb, short* __restrict__ ET,
                   float* __restrict__ enorm, float* __restrict__ enormB) {
    int t = threadIdx.x;
    int k = blockIdx.x * 4 + (t >> 6);
    int l = t & 63;
    float4 v = *(const float4*)(emb + (size_t)k * D_ + l * 4);
    float sum = v.x*v.x + v.y*v.y + v.z*v.z + v.w*v.w;
    for (int m = 1; m < 64; m <<= 1) sum += __shfl_xor(sum, m, 64);
    if (l == 0) { enorm[k] = sum; enormB[k] = sum + BIAS_; }
    bf16x4 o;
    o[0] = (short)f2bf(v.x); o[1] = (short)f2bf(v.y);
    o[2] = (short)f2bf(v.z); o[3] = (short)f2bf(v.w);
    *(bf16x4*)(ET + (size_t)k * D_ + l * 4) = o;
}

// fused: z -> zpart chunks (verified 16x16 tree) + plain bf16 ZT
__global__ __launch_bounds__(256)
void zpart_cvtz_p(const float* __restrict__ z, float* __restrict__ zpart,
                  short* __restrict__ ZT) {
    int bx  = blockIdx.x;           // dcb4*64 + stile
    int dcb = bx >> 6;              // 64-d quarter
    int st  = bx & 63;
    int t   = threadIdx.x;
    int n   = st * 256 + t;
    int b   = n >> 10;
    int s   = n & 1023;
    const float* zb = z + (size_t)b * ZB + (size_t)(dcb * 64) * SP + s;
    short* dst = ZT + (size_t)n * D_ + dcb * 64;
#pragma unroll
    for (int c2 = 0; c2 < 4; ++c2) {
        float vv[16];
#pragma unroll
        for (int dd = 0; dd < 16; ++dd)
            vv[dd] = zb[(size_t)(c2 * 16 + dd) * SP];
        float sum = 0.f;
#pragma unroll
        for (int dd = 0; dd < 16; ++dd) {
            float v = vv[dd];
            sum += v * v;
        }
        zpart[(size_t)(dcb * 4 + c2) * N_TOT + n] = sum;
        bf16x8 o0, o1;
#pragma unroll
        for (int j = 0; j < 8; ++j) { o0[j] = (short)f2bf(vv[j]);
                                      o1[j] = (short)f2bf(vv[8 + j]); }
        *(bf16x8*)(dst + c2 * 16)     = o0;
        *(bf16x8*)(dst + c2 * 16 + 8) = o1;
    }
}

// staging offset (shorts) for row-major [row][256] with per-row chunk swizzle
__device__ __forceinline__ int stg_off(int base_row, int idx) {
    int r  = idx >> 2;
    int lc = (idx & 3) ^ ((r >> 1) & 3);
    return (base_row + r) * 256 + lc * 8;
}

// 256x256 tile, BK=32, 8 K-stages, LDS double-buffered (2 x (16KB A + 16KB B)).
// 8 waves: wm in 0..3 (64-code quarter), wn in 0..1 (128-row half).
// Output: top-2 packed keys per (row, 256-code block) -> pv[cb][n].
__global__ __launch_bounds__(512, 2)
void mfma_argmin3(const short* __restrict__ ET, const short* __restrict__ ZT,
                  const float* __restrict__ enormB, uint2* __restrict__ pv) {
    __shared__ char smem[65536];
    const int t    = threadIdx.x;
    const int wid  = t >> 6, lane = t & 63;
    const int quad = lane >> 4, l16 = lane & 15;
    const int wm   = wid & 3, wn = wid >> 2;
    const int cb     = blockIdx.x & 31;
    const int rb     = blockIdx.x >> 5;
    const int c_base = cb * 256, n_base = rb * 256;

    const int offA0 = stg_off(c_base, t);
    const int offA1 = stg_off(c_base, t + 512);
    const int offB0 = stg_off(n_base, t);
    const int offB1 = stg_off(n_base, t + 512);

#define ISSUE_STAGE(dcb, h) { \
    char* As_ = smem + (h) * 32768; \
    char* Bs_ = As_ + 16384; \
    GLOAD_LDS16(ET + offA0 + (dcb) * 32, As_ + t * 16); \
    GLOAD_LDS16(ET + offA1 + (dcb) * 32, As_ + 8192 + t * 16); \
    GLOAD_LDS16(ZT + offB0 + (dcb) * 32, Bs_ + t * 16); \
    GLOAD_LDS16(ZT + offB1 + (dcb) * 32, Bs_ + 8192 + t * 16); }

    f32x4 acc[4][8];
#pragma unroll
    for (int fi = 0; fi < 4; ++fi)
#pragma unroll
        for (int fj = 0; fj < 8; ++fj) acc[fi][fj] = (f32x4){0.f, 0.f, 0.f, 0.f};

    const int ch = (quad ^ ((l16 >> 1) & 3)) * 16;   // swizzled 16B chunk
    ISSUE_STAGE(0, 0);
    __syncthreads();
#pragma unroll 1
    for (int s = 0; s < 8; ++s) {
        if (s < 7) ISSUE_STAGE(s + 1, (s + 1) & 1);
        const char* As = smem + (s & 1) * 32768;
        const char* Bs = As + 16384;
        bf16x8 a[4];
#pragma unroll
        for (int fi = 0; fi < 4; ++fi)
            a[fi] = *(const bf16x8*)(As + (wm * 64 + fi * 16 + l16) * 64 + ch);
#pragma unroll
        for (int fj = 0; fj < 8; ++fj) {
            bf16x8 bv = *(const bf16x8*)(Bs + (wn * 128 + fj * 16 + l16) * 64 + ch);
#pragma unroll
            for (int fi = 0; fi < 4; ++fi)
                acc[fi][fj] = __builtin_amdgcn_mfma_f32_16x16x32_bf16(
                    a[fi], bv, acc[fi][fj], 0, 0, 0);
        }
        __syncthreads();
    }
#undef ISSUE_STAGE

    // epilogue: packed keys (identical arithmetic to proven rounds 3-5)
    unsigned r1[8], r2[8];
#pragma unroll
    for (int fj = 0; fj < 8; ++fj) { r1[fj] = 0xFFFFFFFFu; r2[fj] = 0xFFFFFFFFu; }
    float ekv[4][4];
#pragma unroll
    for (int fi = 0; fi < 4; ++fi) {
        float4 e4 = *(const float4*)(enormB + c_base + wm * 64 + fi * 16 + quad * 4);
        ekv[fi][0]=e4.x; ekv[fi][1]=e4.y; ekv[fi][2]=e4.z; ekv[fi][3]=e4.w;
    }
#pragma unroll
    for (int fj = 0; fj < 8; ++fj) {
#pragma unroll
        for (int fi = 0; fi < 4; ++fi) {
            const unsigned cbs = (unsigned)(c_base + wm * 64 + fi * 16 + quad * 4);
            float s0 = fmaf(-2.f, acc[fi][fj].x, ekv[fi][0]);
            float s1 = fmaf(-2.f, acc[fi][fj].y, ekv[fi][1]);
            float s2 = fmaf(-2.f, acc[fi][fj].z, ekv[fi][2]);
            float s3 = fmaf(-2.f, acc[fi][fj].w, ekv[fi][3]);
            unsigned k0 = (__float_as_uint(s0) & 0xFFFFE000u) | (cbs + 0u);
            unsigned k1 = (__float_as_uint(s1) & 0xFFFFE000u) | (cbs + 1u);
            unsigned k2 = (__float_as_uint(s2) & 0xFFFFE000u) | (cbs + 2u);
            unsigned k3 = (__float_as_uint(s3) & 0xFFFFE000u) | (cbs + 3u);
            unsigned lo1 = min(k0, k1), hi1 = max(k0, k1);
            unsigned lo2 = min(k2, k3), hi2 = max(k2, k3);
            merge2(lo1, hi1, lo2, hi2);
            merge2(r1[fj], r2[fj], lo1, hi1);
        }
    }
    uint2* mbuf = (uint2*)smem;     // [4 wm][256 rows], 8KB (post-loop reuse)
#pragma unroll
    for (int fj = 0; fj < 8; ++fj) {
        unsigned a1 = r1[fj], a2 = r2[fj];
#pragma unroll
        for (int m = 16; m <= 32; m <<= 1) {
            unsigned b1 = __shfl_xor(a1, m, 64);
            unsigned b2 = __shfl_xor(a2, m, 64);
            merge2(a1, a2, b1, b2);
        }
        if (quad == 0)
            mbuf[wm * 256 + wn * 128 + fj * 16 + l16] = make_uint2(a1, a2);
    }
    __syncthreads();
    if (t < 256) {
        uint2 P = mbuf[t];
        unsigned a1 = P.x, a2 = P.y;
#pragma unroll
        for (int g = 1; g < 4; ++g) {
            uint2 Q = mbuf[g * 256 + t];
            merge2(a1, a2, Q.x, Q.y);
        }
        pv[(size_t)cb * N_TOT + n_base + t] = make_uint2(a1, a2);
    }
}

// ================== templated phaseA / recheck (NG groups) ==================

template <int NG>
__global__ __launch_bounds__(256)
void reduce_phaseA_t(const uint2* __restrict__ pv, int* __restrict__ fidx,
                     float* __restrict__ out_idx, int* __restrict__ wl,
                     int* __restrict__ wl_cnt, float* __restrict__ out_loss) {
    int n = blockIdx.x * 256 + threadIdx.x;
    if (n == 0) *out_loss = 0.f;
    uint2 pp[NG];
    unsigned mn = 0xFFFFFFFFu;
#pragma unroll
    for (int g = 0; g < NG; ++g) {
        pp[g] = pv[(size_t)g * N_TOT + n];
        mn = min(mn, pp[g].x);
    }
    float smin  = __uint_as_float(mn & 0xFFFFE000u);
    unsigned th = __float_as_uint(smin + DELTA_) | 8191u;
    int cnt = 0;
#pragma unroll
    for (int g = 0; g < NG; ++g) {
        cnt += (pp[g].x <= th) ? 1 : 0;
        cnt += (pp[g].y <= th) ? 1 : 0;
    }
    if (cnt > 1) {
        int slot = atomicAdd(wl_cnt, 1);
        wl[slot] = n;
    } else {
        int c = (int)(mn & 8191u);
        fidx[n] = c;
        out_idx[n] = (float)c;
    }
}

// one wave per recheck row; exact fp32 dot chain IDENTICAL to rounds 1-5.
template <int NG>
__global__ __launch_bounds__(256)
void recheck_t(const uint2* __restrict__ pv, const float* __restrict__ znorm,
               const float* __restrict__ enorm, const float* __restrict__ z,
               const float* __restrict__ emb, const int* __restrict__ wl,
               const int* __restrict__ wl_cnt, int* __restrict__ fidx,
               float* __restrict__ out_idx) {
    __shared__ float zrow[4][256];
    const int lane = threadIdx.x & 63;
    const int wslot = threadIdx.x >> 6;
    const int gwave = (blockIdx.x * 256 + threadIdx.x) >> 6;
    const int nwaves = (gridDim.x * 256) >> 6;
    const int total = *wl_cnt;

    for (int i = gwave; i < total; i += nwaves) {
        int n = wl[i];
        unsigned key = 0xFFFFFFFFu;
        if (lane < 2 * NG) {
            uint2 p = pv[(size_t)(lane >> 1) * N_TOT + n];
            key = (lane & 1) ? p.y : p.x;
        }
        unsigned mn = key;
#pragma unroll
        for (int m = 1; m < 64; m <<= 1) mn = min(mn, __shfl_xor(mn, m, 64));
        float smin  = __uint_as_float(mn & 0xFFFFE000u);
        unsigned th = __float_as_uint(smin + DELTA_) | 8191u;

        const int b = n >> 10, sp = n & 1023;
        const float* zr = z + (size_t)b * ZB + sp;
#pragma unroll
        for (int j = 0; j < 4; ++j)
            zrow[wslot][lane + j * 64] = zr[(size_t)(lane + j * 64) * SP];
        float zn = znorm[n];

        unsigned lexlo = 0xFFFFFFFFu, lexhi = 0xFFFFFFFFu;
        if (key <= th) {
            int c = (int)(key & 8191u);
            const float* er = emb + (size_t)c * D_;
            float dot = 0.f;
#pragma unroll 8
            for (int d = 0; d < D_; ++d)
                dot = fmaf(zrow[wslot][d], er[d], dot);
            float s = (zn + enorm[c]) - 2.f * dot;
            unsigned sb = __float_as_uint(s);
            lexhi = sb >> 19;
            lexlo = (sb << 13) | (unsigned)c;
        }
#pragma unroll
        for (int m = 1; m < 64; m <<= 1) {
            unsigned olo = __shfl_xor(lexlo, m, 64);
            unsigned ohi = __shfl_xor(lexhi, m, 64);
            if (ohi < lexhi || (ohi == lexhi && olo < lexlo)) { lexhi = ohi; lexlo = olo; }
        }
        if (lane == 0) {
            int c = (int)(lexlo & 8191u);
            fidx[n] = c;
            out_idx[n] = (float)c;
        }
    }
}

// =====================================================================
// ================  MID tier (round-5 exact, proven)  =================
// =====================================================================

__global__ __launch_bounds__(256)
void cvt_e_enorm(const float* __restrict__ emb, short* __restrict__ ET3,
                 float* __restrict__ enorm, float* __restrict__ enormB) {
    int t = threadIdx.x;
    int k = blockIdx.x * 4 + (t >> 6);
    int l = t & 63;
    float4 v = *(const float4*)(emb + (size_t)k * D_ + l * 4);
    float sum = v.x*v.x + v.y*v.y + v.z*v.z + v.w*v.w;
    for (int m = 1; m < 64; m <<= 1) sum += __shfl_xor(sum, m, 64);
    if (l == 0) { enorm[k] = sum; enormB[k] = sum + BIAS_; }
    int dcb  = l >> 4;
    int c    = (l >> 1) & 7;
    int half = l & 1;
    bf16x4 o;
    o[0] = (short)f2bf(v.x); o[1] = (short)f2bf(v.y);
    o[2] = (short)f2bf(v.z); o[3] = (short)f2bf(v.w);
    *(bf16x4*)(ET3 + ((size_t)dcb * K_ + k) * 64 + ((c ^ (k & 7)) * 8) + half * 4) = o;
}

__global__ __launch_bounds__(256)
void zpart_cvtz(const float* __restrict__ z, float* __restrict__ zpart,
                short* __restrict__ ZT3) {
    int bx  = blockIdx.x;
    int dcb = bx >> 6;
    int st  = bx & 63;
    int t   = threadIdx.x;
    int n   = st * 256 + t;
    int b   = n >> 10;
    int s   = n & 1023;
    const float* zb = z + (size_t)b * ZB + (size_t)(dcb * 64) * SP + s;
    short* dst = ZT3 + ((size_t)dcb * N_TOT + n) * 64;
    int sw = n & 7;
#pragma unroll
    for (int c2 = 0; c2 < 4; ++c2) {
        float vv[16];
#pragma unroll
        for (int dd = 0; dd < 16; ++dd)
            vv[dd] = zb[(size_t)(c2 * 16 + dd) * SP];
        float sum = 0.f;
#pragma unroll
        for (int dd = 0; dd < 16; ++dd) {
            float v = vv[dd];
            sum += v * v;
        }
        zpart[(size_t)(dcb * 4 + c2) * N_TOT + n] = sum;
        bf16x8 o0, o1;
#pragma unroll
        for (int j = 0; j < 8; ++j) { o0[j] = (short)f2bf(vv[j]);
                                      o1[j] = (short)f2bf(vv[8 + j]); }
        *(bf16x8*)(dst + (((c2 * 2)     ^ sw) * 8)) = o0;
        *(bf16x8*)(dst + (((c2 * 2 + 1) ^ sw) * 8)) = o1;
    }
}

__global__ __launch_bounds__(256, 4)
void mfma_argmin2(const short* __restrict__ ET3, const short* __restrict__ ZT3,
                  const float* __restrict__ enormB, uint2* __restrict__ pv) {
    __shared__ char smem[32768];
    const int t    = threadIdx.x;
    const int wid  = t >> 6, lane = t & 63;
    const int quad = lane >> 4, l16 = lane & 15;
    const int wm   = wid >> 1, wn = wid & 1;
    const int stripe = blockIdx.x >> 7;
    const int n0     = (blockIdx.x & 127) * 128;
    const int swz    = (l16 & 7);

    unsigned r1[4], r2[4];
#pragma unroll
    for (int fj = 0; fj < 4; ++fj) { r1[fj] = 0xFFFFFFFFu; r2[fj] = 0xFFFFFFFFu; }

#pragma unroll 1
    for (int cc = 0; cc < 8; ++cc) {
        const int c0 = stripe * 1024 + cc * 128;
        f32x4 acc[4][4];
#pragma unroll
        for (int fi = 0; fi < 4; ++fi)
#pragma unroll
            for (int fj = 0; fj < 4; ++fj) acc[fi][fj] = (f32x4){0.f, 0.f, 0.f, 0.f};

#pragma unroll 1
        for (int dcb = 0; dcb < 4; ++dcb) {
            __syncthreads();
            const char* gA = (const char*)ET3 + ((size_t)dcb * K_    + c0) * 128;
            const char* gB = (const char*)ZT3 + ((size_t)dcb * N_TOT + n0) * 128;
#pragma unroll
            for (int j = 0; j < 4; ++j) {
                int off = j * 4096 + t * 16;
                GLOAD_LDS16(gA + off, smem + off);
                GLOAD_LDS16(gB + off, smem + 16384 + off);
            }
            __syncthreads();
#pragma unroll
            for (int dc2 = 0; dc2 < 2; ++dc2) {
                bf16x8 af[4], bfv[4];
                const int chm = ((dc2 * 4 + quad) ^ swz) * 16;
#pragma unroll
                for (int fi = 0; fi < 4; ++fi)
                    af[fi] = *(const bf16x8*)(smem + (wm*64 + fi*16 + l16)*128 + chm);
#pragma unroll
                for (int fj = 0; fj < 4; ++fj)
                    bfv[fj] = *(const bf16x8*)(smem + 16384 + (wn*64 + fj*16 + l16)*128 + chm);
#pragma unroll
                for (int fi = 0; fi < 4; ++fi)
#pragma unroll
                    for (int fj = 0; fj < 4; ++fj)
                        acc[fi][fj] = __builtin_amdgcn_mfma_f32_16x16x32_bf16(
                            af[fi], bfv[fj], acc[fi][fj], 0, 0, 0);
            }
        }

        float ekv[4][4];
#pragma unroll
        for (int fi = 0; fi < 4; ++fi) {
            float4 e4 = *(const float4*)(enormB + c0 + wm*64 + fi*16 + quad*4);
            ekv[fi][0]=e4.x; ekv[fi][1]=e4.y; ekv[fi][2]=e4.z; ekv[fi][3]=e4.w;
        }
#pragma unroll
        for (int fj = 0; fj < 4; ++fj) {
#pragma unroll
            for (int fi = 0; fi < 4; ++fi) {
                const unsigned cb = (unsigned)(c0 + wm*64 + fi*16 + quad*4);
                float s0 = fmaf(-2.f, acc[fi][fj].x, ekv[fi][0]);
                float s1 = fmaf(-2.f, acc[fi][fj].y, ekv[fi][1]);
                float s2 = fmaf(-2.f, acc[fi][fj].z, ekv[fi][2]);
                float s3 = fmaf(-2.f, acc[fi][fj].w, ekv[fi][3]);
                unsigned k0 = (__float_as_uint(s0) & 0xFFFFE000u) | (cb + 0u);
                unsigned k1 = (__float_as_uint(s1) & 0xFFFFE000u) | (cb + 1u);
                unsigned k2 = (__float_as_uint(s2) & 0xFFFFE000u) | (cb + 2u);
                unsigned k3 = (__float_as_uint(s3) & 0xFFFFE000u) | (cb + 3u);
                unsigned lo1 = min(k0, k1), hi1 = max(k0, k1);
                unsigned lo2 = min(k2, k3), hi2 = max(k2, k3);
                merge2(lo1, hi1, lo2, hi2);
                merge2(r1[fj], r2[fj], lo1, hi1);
            }
        }
    }

#pragma unroll
    for (int fj = 0; fj < 4; ++fj) {
        unsigned a1 = r1[fj], a2 = r2[fj];
#pragma unroll
        for (int m = 16; m <= 32; m <<= 1) {
            unsigned b1 = __shfl_xor(a1, m, 64);
            unsigned b2 = __shfl_xor(a2, m, 64);
            merge2(a1, a2, b1, b2);
        }
        if (quad == 0) {
            int n = n0 + wn*64 + fj*16 + l16;
            pv[(size_t)(stripe * 2 + wm) * N_TOT + n] = make_uint2(a1, a2);
        }
    }
}

// =====================================================================
// =========================  shared kernels  ==========================
// =====================================================================

__global__ __launch_bounds__(256)
void znorm_kernel2(const float* __restrict__ zpart, float* __restrict__ znorm,
                   int* __restrict__ wl_cnt) {
    int n = blockIdx.x * 256 + threadIdx.x;
    float sum = 0.f;
#pragma unroll
    for (int dc = 0; dc < 16; ++dc) sum += zpart[(size_t)dc * N_TOT + n];
    znorm[n] = sum;
    if (n == 0) *wl_cnt = 0;
}

__global__ __launch_bounds__(256)
void output_kernel2(const float* __restrict__ z, const float* __restrict__ emb,
                    const int* __restrict__ fidx, float* __restrict__ out,
                    float* __restrict__ loss) {
    __shared__ float eL[32][257];
    __shared__ int   fid[32];
    __shared__ float red[4];
    const int nb = blockIdx.x;
    const int n0 = nb * 32;
    const int b  = n0 >> 10;
    const int s0 = n0 & 1023;
    const int t  = threadIdx.x;
    if (t < 32) fid[t] = fidx[n0 + t];
    __syncthreads();
#pragma unroll
    for (int i = 0; i < 8; ++i) {
        int p = t + i * 256;
        int row = p >> 6, q = p & 63;
        float4 v = *(const float4*)(emb + (size_t)fid[row] * D_ + q * 4);
        eL[row][q*4+0] = v.x; eL[row][q*4+1] = v.y;
        eL[row][q*4+2] = v.z; eL[row][q*4+3] = v.w;
    }
    __syncthreads();
    const int sl = t & 31, dg = t >> 5;
    float lsum = 0.f;
#pragma unroll
    for (int i = 0; i < 32; ++i) {
        int d = dg * 32 + i;
        size_t off = ((size_t)(b * D_ + d)) * SP + s0 + sl;
        float zv = z[off];
        float q  = eL[sl][d];
        float diff = q - zv;
        out[off] = zv + diff;
        lsum += diff * diff;
    }
    for (int m = 1; m < 64; m <<= 1) lsum += __shfl_xor(lsum, m, 64);
    if ((t & 63) == 0) red[t >> 6] = lsum;
    __syncthreads();
    if (t == 0) {
        float tot = (red[0] + red[1] + red[2] + red[3])
                    * (1.25f / (float)(B_ * SP * D_));
        atomicAdd(loss, tot);
    }
}

// =====================================================================
// ============================  launch  ===============================
// =====================================================================
// BIG layout (floats):
//   enorm [0,8192) enormB [8192,16384) znorm [16384,32768) fidx [32768,49152)
//   wl_cnt 49152 (pad 49216) wl [49216,65600) (pad 65664)
//   pv32 [65664,1114240)  (32 groups x 16384 uint2; zpart aliases head)
//   ET   [1114240,2162816)  ZT [2162816,4259968)
//   NEED_BIG = 17,039,872 B
// MID layout: identical to round-5 proven (NEED_MID = 14,942,720 B)

extern "C" void kernel_launch(void* const* d_in, const int* in_sizes, int n_in,
                              void* d_out, int out_size, void* d_ws, size_t ws_size,
                              hipStream_t stream) {
    const float* z   = (const float*)d_in[0];
    const float* emb = (const float*)d_in[1];
    float* out = (float*)d_out;
    float* w   = (float*)d_ws;

    float* enorm  = w;
    float* enormB = w + 8192;
    float* znorm  = w + 16384;
    int*   fidx   = (int*)(w + 32768);
    int*   wl_cnt = (int*)(w + 49152);
    int*   wl     = (int*)(w + 49216);

    float* out0     = out;
    float* out_loss = out + (size_t)B_ * D_ * SP;
    float* out_idx  = out_loss + 1;

    const size_t NEED_BIG = 4259968ULL * 4ULL;
    if (ws_size >= NEED_BIG) {
        uint2* pv    = (uint2*)(w + 65664);
        float* zpart = w + 65664;              // aliases pv (dead before pv written)
        short* ET    = (short*)(w + 1114240);
        short* ZT    = (short*)(w + 2162816);

        cvt_e_enorm_p<<<K_ / 4, 256, 0, stream>>>(emb, ET, enorm, enormB);
        zpart_cvtz_p<<<256, 256, 0, stream>>>(z, zpart, ZT);
        znorm_kernel2<<<N_TOT / 256, 256, 0, stream>>>(zpart, znorm, wl_cnt);
        mfma_argmin3<<<2048, 512, 0, stream>>>(ET, ZT, enormB, pv);
        reduce_phaseA_t<32><<<N_TOT / 256, 256, 0, stream>>>(pv, fidx, out_idx,
                                                             wl, wl_cnt, out_loss);
        recheck_t<32><<<256, 256, 0, stream>>>(pv, znorm, enorm, z, emb,
                                               wl, wl_cnt, fidx, out_idx);
    } else {
        // round-5 proven fast path
        uint2* pv    = (uint2*)(w + 65664);
        float* zpart = w + 65664;
        short* ET3   = (short*)(w + 589952);
        short* ZT3   = (short*)(w + 1638528);

        cvt_e_enorm<<<K_ / 4, 256, 0, stream>>>(emb, ET3, enorm, enormB);
        zpart_cvtz<<<256, 256, 0, stream>>>(z, zpart, ZT3);
        znorm_kernel2<<<N_TOT / 256, 256, 0, stream>>>(zpart, znorm, wl_cnt);
        mfma_argmin2<<<1024, 256, 0, stream>>>(ET3, ZT3, enormB, pv);
        reduce_phaseA_t<16><<<N_TOT / 256, 256, 0, stream>>>(pv, fidx, out_idx,
                                                             wl, wl_cnt, out_loss);
        recheck_t<16><<<256, 256, 0, stream>>>(pv, znorm, enorm, z, emb,
                                               wl, wl_cnt, fidx, out_idx);
    }
    output_kernel2<<<N_TOT / 32, 256, 0, stream>>>(z, emb, fidx, out0, out_loss);
}